// Round 3
// baseline (300.794 us; speedup 1.0000x reference)
//
#include <hip/hip_runtime.h>
#include <hip/hip_bf16.h>
#include <stdint.h>

// CriticNetwork reduction:
//   value[b,i,m] = ve[i] + (sv[i] + w[i,m]*dv[m]) / N
//   weights5[b,i,m,j] = w[b,i,j]            (broadcast over m)
// where  w = sigmoid((oa Wq^T)(oa Wk^T)^T / sqrt(128)) with scores[i,j]=q[j].k[i],
//   u = Wv^T wf2 (144), g = Wenc^T wf1 (128),
//   va_s[j]=oa[j].u, dv[m]=(pol[m]-act[m]).u[128:144], ve[i]=obs[i].g,
//   sv[i]=sum_j w[i,j] va_s[j].
// Inputs float32, OUTPUT float32 (reference returns f32; R1 NaN proved inputs
// are f32; R2's 1.85 error (> all-zero 1.17) proved output buffer is f32 —
// bf16 writes filled half the buffer and left the tail zero).

#define BB 128
#define NN 64
#define OBSD 128
#define ACTD 16
#define DD 144
#define DKD 128

__global__ __launch_bounds__(512, 1) void critic_main(
    const float* __restrict__ obs, const float* __restrict__ pol, const float* __restrict__ act,
    const float* __restrict__ Wk, const float* __restrict__ Wq, const float* __restrict__ Wv,
    const float* __restrict__ Wenc, const float* __restrict__ Wfin,
    float* __restrict__ out)
{
  // pads: s_oa stride 148 (16B-aligned rows), s_k/s_q stride 132
  // (16B-aligned float4 reads in scores), s_w stride 65 (conflict-free).
  __shared__ __align__(16) float s_oa[NN][148];
  __shared__ __align__(16) float s_k[NN][132];
  __shared__ __align__(16) float s_q[NN][132];
  __shared__ float s_w[NN][65];
  __shared__ float s_dpa[NN][ACTD];
  __shared__ float s_u[DD];
  __shared__ float s_g[OBSD];
  __shared__ float s_vas[NN];
  __shared__ float s_ve[NN];
  __shared__ float s_dv[NN];
  __shared__ float s_sv[NN];

  const int tid = threadIdx.x;
  const int b = blockIdx.x;

  // ---- stage obs -> s_oa[:,0:128] (float4)
  {
    const float4* obs4 = (const float4*)(obs + (size_t)b * NN * OBSD);
    for (int idx = tid; idx < NN * OBSD / 4; idx += 512) {
      float4 v = obs4[idx];
      int i = idx >> 5, d0 = (idx & 31) * 4;       // 32 float4 per row
      s_oa[i][d0 + 0] = v.x; s_oa[i][d0 + 1] = v.y;
      s_oa[i][d0 + 2] = v.z; s_oa[i][d0 + 3] = v.w;
    }
  }
  // ---- stage act -> s_oa[:,128:144]; (pol-act) -> s_dpa
  {
    const float4* act4 = (const float4*)(act + (size_t)b * NN * ACTD);
    const float4* pol4 = (const float4*)(pol + (size_t)b * NN * ACTD);
    for (int idx = tid; idx < NN * ACTD / 4; idx += 512) {
      float4 a = act4[idx], p = pol4[idx];
      int i = idx >> 2, t0 = (idx & 3) * 4;        // 4 float4 per row
      s_oa[i][OBSD + t0 + 0] = a.x; s_oa[i][OBSD + t0 + 1] = a.y;
      s_oa[i][OBSD + t0 + 2] = a.z; s_oa[i][OBSD + t0 + 3] = a.w;
      s_dpa[i][t0 + 0] = p.x - a.x; s_dpa[i][t0 + 1] = p.y - a.y;
      s_dpa[i][t0 + 2] = p.z - a.z; s_dpa[i][t0 + 3] = p.w - a.w;
    }
  }
  // ---- u[144] = Wv^T wf2 ; g[128] = Wenc^T wf1 (redundant per block, tiny)
  if (tid < DD) {
    float acc = 0.f;
    for (int c = 0; c < DKD; ++c) acc += Wv[(size_t)c * DD + tid] * Wfin[OBSD + c];
    s_u[tid] = acc;
  } else if (tid < DD + OBSD) {
    const int d = tid - DD;
    float acc = 0.f;
    for (int c = 0; c < 128; ++c) acc += Wenc[(size_t)c * OBSD + d] * Wfin[c];
    s_g[d] = acc;
  }
  __syncthreads();

  // ---- K,Q = oa @ W^T : lanes over i (wave-broadcast W loads), 16 c per thread
  {
    const int i = tid & 63;
    const int c0 = (tid >> 6) * 16;
    float acck[16], accq[16];
    #pragma unroll
    for (int cc = 0; cc < 16; ++cc) { acck[cc] = 0.f; accq[cc] = 0.f; }
    for (int d0 = 0; d0 < DD; d0 += 16) {
      float o[16];
      const float4* op = (const float4*)&s_oa[i][d0];
      float4 v0 = op[0], v1 = op[1], v2 = op[2], v3 = op[3];
      o[0]=v0.x; o[1]=v0.y; o[2]=v0.z; o[3]=v0.w;
      o[4]=v1.x; o[5]=v1.y; o[6]=v1.z; o[7]=v1.w;
      o[8]=v2.x; o[9]=v2.y; o[10]=v2.z; o[11]=v2.w;
      o[12]=v3.x; o[13]=v3.y; o[14]=v3.z; o[15]=v3.w;
      #pragma unroll
      for (int cc = 0; cc < 16; ++cc) {
        const int c = c0 + cc;
        const float4* wk4 = (const float4*)(Wk + (size_t)c * DD + d0);
        const float4* wq4 = (const float4*)(Wq + (size_t)c * DD + d0);
        float4 ka = wk4[0], kb = wk4[1], kc = wk4[2], kd = wk4[3];
        float4 qa = wq4[0], qb = wq4[1], qc = wq4[2], qd = wq4[3];
        float sk =
          o[0]*ka.x + o[1]*ka.y + o[2]*ka.z + o[3]*ka.w +
          o[4]*kb.x + o[5]*kb.y + o[6]*kb.z + o[7]*kb.w +
          o[8]*kc.x + o[9]*kc.y + o[10]*kc.z + o[11]*kc.w +
          o[12]*kd.x + o[13]*kd.y + o[14]*kd.z + o[15]*kd.w;
        float sq =
          o[0]*qa.x + o[1]*qa.y + o[2]*qa.z + o[3]*qa.w +
          o[4]*qb.x + o[5]*qb.y + o[6]*qb.z + o[7]*qb.w +
          o[8]*qc.x + o[9]*qc.y + o[10]*qc.z + o[11]*qc.w +
          o[12]*qd.x + o[13]*qd.y + o[14]*qd.z + o[15]*qd.w;
        acck[cc] += sk; accq[cc] += sq;
      }
    }
    #pragma unroll
    for (int cc = 0; cc < 16; ++cc) { s_k[i][c0 + cc] = acck[cc]; s_q[i][c0 + cc] = accq[cc]; }
  }
  // ---- small per-row sums (depend only on pre-barrier LDS)
  if (tid < 64) {
    float acc = 0.f;
    for (int d = 0; d < DD; ++d) acc += s_oa[tid][d] * s_u[d];
    s_vas[tid] = acc;
  } else if (tid < 128) {
    const int i = tid - 64;
    float acc = 0.f;
    for (int d = 0; d < OBSD; ++d) acc += s_oa[i][d] * s_g[d];
    s_ve[i] = acc;
  } else if (tid < 192) {
    const int i = tid - 128;
    float acc = 0.f;
    #pragma unroll
    for (int t = 0; t < ACTD; ++t) acc += s_dpa[i][t] * s_u[OBSD + t];
    s_dv[i] = acc;
  }
  __syncthreads();

  // ---- scores[i,j] = q[j].k[i]; w = sigmoid(scores/sqrt(128))
  for (int x = tid; x < NN * NN; x += 512) {
    const int j = x & 63, i = x >> 6;
    float acc = 0.f;
    for (int d = 0; d < DKD; d += 4) {
      float4 qv = *(const float4*)&s_q[j][d];
      float4 kv = *(const float4*)&s_k[i][d];
      acc += qv.x * kv.x + qv.y * kv.y + qv.z * kv.z + qv.w * kv.w;
    }
    const float s = acc * 0.08838834764831845f;  // 1/sqrt(128)
    s_w[i][j] = 1.0f / (1.0f + __expf(-s));
  }
  __syncthreads();

  if (tid < 64) {
    float acc = 0.f;
    for (int j = 0; j < NN; ++j) acc += s_w[tid][j] * s_vas[j];
    s_sv[tid] = acc;
  }
  __syncthreads();

  // ---- outputs (f32): value [b,i,m] and the m=0 plane of weights5
  float* val_out = out + (size_t)b * NN * NN;
  float* w5_out  = out + (size_t)BB * NN * NN + (size_t)b * NN * NN * NN;
  for (int x = tid; x < NN * NN; x += 512) {
    const int m = x & 63, i = x >> 6;
    val_out[x] = s_ve[i] + (s_sv[i] + s_w[i][m] * s_dv[m]) * (1.0f / 64.0f);
  }
  for (int x = tid; x < NN * NN; x += 512) {
    const int j = x & 63, i = x >> 6;
    w5_out[(size_t)i * (NN * NN) + j] = s_w[i][j];
  }
}

// Broadcast w[b,i,:] (64 f32 = 16 float4, already at m=0) to all 64 m-planes.
// One block per (b,i); fully coalesced 16B stores; write-bound (~134 MB).
__global__ __launch_bounds__(256, 4) void bcast_w(float* __restrict__ out) {
  float4* dst = (float4*)(out + (size_t)BB * NN * NN + (size_t)blockIdx.x * NN * NN);
  const int j4 = threadIdx.x & 15;           // 16 float4 per j-row
  const int m0 = threadIdx.x >> 4;           // 0..15
  const float4 v = dst[j4];                  // m=0 row (benign same-value rewrite)
  dst[(size_t)(m0 +  0) * 16 + j4] = v;
  dst[(size_t)(m0 + 16) * 16 + j4] = v;
  dst[(size_t)(m0 + 32) * 16 + j4] = v;
  dst[(size_t)(m0 + 48) * 16 + j4] = v;
}

extern "C" void kernel_launch(void* const* d_in, const int* in_sizes, int n_in,
                              void* d_out, int out_size, void* d_ws, size_t ws_size,
                              hipStream_t stream) {
  (void)in_sizes; (void)n_in; (void)out_size; (void)d_ws; (void)ws_size;
  const float* obs  = (const float*)d_in[0];
  const float* pol  = (const float*)d_in[1];
  const float* act  = (const float*)d_in[2];
  const float* Wk   = (const float*)d_in[3];
  const float* Wq   = (const float*)d_in[4];
  const float* Wv   = (const float*)d_in[5];
  const float* Wenc = (const float*)d_in[6];
  const float* Wfin = (const float*)d_in[7];
  float* out = (float*)d_out;
  hipLaunchKernelGGL(critic_main, dim3(BB), dim3(512), 0, stream,
                     obs, pol, act, Wk, Wq, Wv, Wenc, Wfin, out);
  hipLaunchKernelGGL(bcast_w, dim3(BB * NN), dim3(256), 0, stream, out);
}

// Round 4
// 194.953 us; speedup vs baseline: 1.5429x; 1.5429x over previous
//
#include <hip/hip_runtime.h>
#include <stdint.h>

// CriticNetwork reduction (verified passing in R3):
//   value[b,i,m] = ve[i] + (sv[i] + w[i,m]*dv[m]) / N      (written by kernel A)
//   weights5[b,i,m,j] = w[b,i,j]  (broadcast over m)       (written by kernel C)
// w = sigmoid((oa Wk^T)(oa Wq^T)^T-ish: sc[i,j] = k[i].q[j], /sqrt(128))
// u = Wv^T wf2 (144), g = Wenc^T wf1 (128), vas[j]=oa[j].u,
// dv[m]=(pol[m]-act[m]).u[128:144], ve[i]=obs[i].g, sv[i]=sum_j w[i,j] vas[j].
// Inputs f32, output f32. d_ws holds only w: 128*64*64 f32 = 2 MB.

#define BB 128
#define NN 64
#define OBSD 128
#define ACTD 16
#define DD 144
#define DKD 128

#define SOA 148   // s_oa row stride (floats), mult of 4 for float4
#define SW  148   // s_W row stride
#define SKQ 132   // s_k/s_q row stride
#define SWW 65    // s_w row stride (conflict-free column walks)

// LDS offsets in floats (total 38416 floats = 150.1 KB <= 160 KB)
#define OFF_OA   0                    // 64*148 = 9472
#define OFF_K    9472                 // 64*132 = 8448
#define OFF_A    17920                // region A: s_W 128*148 = 18944; later s_q (8448) + s_w (4160)
#define OFF_SC   36864
#define OFF_U    (OFF_SC)             // 144
#define OFF_G    (OFF_U + 144)        // 128
#define OFF_VAS  (OFF_G + 128)        // 64
#define OFF_VE   (OFF_VAS + 64)       // 64
#define OFF_DV   (OFF_VE + 64)        // 64
#define OFF_SV   (OFF_DV + 64)        // 64
#define OFF_DPA  (OFF_SV + 64)        // 64*16 = 1024
#define LDS_FLOATS (OFF_DPA + 1024)   // 38416

__global__ __launch_bounds__(512, 1) void critic_a(
    const float* __restrict__ obs, const float* __restrict__ pol, const float* __restrict__ act,
    const float* __restrict__ Wk, const float* __restrict__ Wq, const float* __restrict__ Wv,
    const float* __restrict__ Wenc, const float* __restrict__ Wfin,
    float* __restrict__ out, float* __restrict__ ws)
{
  __shared__ __align__(16) float smem[LDS_FLOATS];
  float* s_oa = smem + OFF_OA;
  float* s_k  = smem + OFF_K;
  float* s_A  = smem + OFF_A;          // Wk/Wq during GEMM passes
  float* s_q  = smem + OFF_A;          // aliased after Wq consumed
  float* s_w  = smem + OFF_A + 8448;   // aliased after Wq consumed
  float* s_u  = smem + OFF_U;
  float* s_g  = smem + OFF_G;
  float* s_vas = smem + OFF_VAS;
  float* s_ve  = smem + OFF_VE;
  float* s_dv  = smem + OFF_DV;
  float* s_sv  = smem + OFF_SV;
  float* s_dpa = smem + OFF_DPA;

  const int tid = threadIdx.x;
  const int b = blockIdx.x;

  // ---------- phase 0: stage oa, dpa; compute u,g from global (coalesced) ----------
  {
    const float4* obs4 = (const float4*)(obs + (size_t)b * NN * OBSD);
    for (int idx = tid; idx < NN * OBSD / 4; idx += 512) {
      float4 v = obs4[idx];
      int i = idx >> 5, d0 = (idx & 31) * 4;
      *(float4*)&s_oa[i * SOA + d0] = v;
    }
    const float4* act4 = (const float4*)(act + (size_t)b * NN * ACTD);
    const float4* pol4 = (const float4*)(pol + (size_t)b * NN * ACTD);
    for (int idx = tid; idx < NN * ACTD / 4; idx += 512) {
      float4 a = act4[idx], p = pol4[idx];
      int i = idx >> 2, t0 = (idx & 3) * 4;
      *(float4*)&s_oa[i * SOA + OBSD + t0] = a;
      s_dpa[i * ACTD + t0 + 0] = p.x - a.x; s_dpa[i * ACTD + t0 + 1] = p.y - a.y;
      s_dpa[i * ACTD + t0 + 2] = p.z - a.z; s_dpa[i * ACTD + t0 + 3] = p.w - a.w;
    }
  }
  if (tid < DD) {
    float a0 = 0.f, a1 = 0.f, a2 = 0.f, a3 = 0.f;
    for (int c = 0; c < DKD; c += 4) {
      a0 += Wv[(size_t)(c + 0) * DD + tid] * Wfin[OBSD + c + 0];
      a1 += Wv[(size_t)(c + 1) * DD + tid] * Wfin[OBSD + c + 1];
      a2 += Wv[(size_t)(c + 2) * DD + tid] * Wfin[OBSD + c + 2];
      a3 += Wv[(size_t)(c + 3) * DD + tid] * Wfin[OBSD + c + 3];
    }
    s_u[tid] = (a0 + a1) + (a2 + a3);
  } else if (tid < DD + OBSD) {
    const int d = tid - DD;
    float a0 = 0.f, a1 = 0.f, a2 = 0.f, a3 = 0.f;
    for (int c = 0; c < 128; c += 4) {
      a0 += Wenc[(size_t)(c + 0) * OBSD + d] * Wfin[c + 0];
      a1 += Wenc[(size_t)(c + 1) * OBSD + d] * Wfin[c + 1];
      a2 += Wenc[(size_t)(c + 2) * OBSD + d] * Wfin[c + 2];
      a3 += Wenc[(size_t)(c + 3) * OBSD + d] * Wfin[c + 3];
    }
    s_g[d] = (a0 + a1) + (a2 + a3);
  }
  __syncthreads();

  // GEMM mapping: cl = lane's base col, wave ig handles rows i0 = ig*8 .. +7.
  const int cl = tid & 63;
  const int ig = tid >> 6;   // wave index (8 waves)

  // ---------- phase 1: K = oa @ Wk^T ----------
  for (int idx = tid; idx < DKD * (DD / 4); idx += 512) {   // stage Wk (128x144)
    int row = idx / 36, col = idx - row * 36;
    *(float4*)&s_A[row * SW + col * 4] = ((const float4*)Wk)[idx];
  }
  __syncthreads();
  {
    float acc[8][2];
    #pragma unroll
    for (int r = 0; r < 8; ++r) { acc[r][0] = 0.f; acc[r][1] = 0.f; }
    #pragma unroll 4
    for (int d0 = 0; d0 < DD; d0 += 4) {
      float4 w0 = *(const float4*)&s_A[cl * SW + d0];
      float4 w1 = *(const float4*)&s_A[(cl + 64) * SW + d0];
      #pragma unroll
      for (int r = 0; r < 8; ++r) {
        float4 o = *(const float4*)&s_oa[(ig * 8 + r) * SOA + d0];
        acc[r][0] += o.x * w0.x + o.y * w0.y + o.z * w0.z + o.w * w0.w;
        acc[r][1] += o.x * w1.x + o.y * w1.y + o.z * w1.z + o.w * w1.w;
      }
    }
    #pragma unroll
    for (int r = 0; r < 8; ++r) {
      s_k[(ig * 8 + r) * SKQ + cl]      = acc[r][0];
      s_k[(ig * 8 + r) * SKQ + cl + 64] = acc[r][1];
    }
  }
  // per-row scalars (read only s_oa/s_u/s_g — safe alongside)
  if (tid < 64) {
    float a = 0.f;
    for (int d = 0; d < DD; ++d) a += s_oa[tid * SOA + d] * s_u[d];
    s_vas[tid] = a;
  } else if (tid < 128) {
    const int i = tid - 64;
    float a = 0.f;
    for (int d = 0; d < OBSD; ++d) a += s_oa[i * SOA + d] * s_g[d];
    s_ve[i] = a;
  } else if (tid < 192) {
    const int i = tid - 128;
    float a = 0.f;
    #pragma unroll
    for (int t = 0; t < ACTD; ++t) a += s_dpa[i * ACTD + t] * s_u[OBSD + t];
    s_dv[i] = a;
  }
  __syncthreads();

  // ---------- phase 2: Q = oa @ Wq^T (into regs), then s_q over the W buffer ----------
  for (int idx = tid; idx < DKD * (DD / 4); idx += 512) {   // stage Wq
    int row = idx / 36, col = idx - row * 36;
    *(float4*)&s_A[row * SW + col * 4] = ((const float4*)Wq)[idx];
  }
  __syncthreads();
  float qacc[8][2];
  {
    #pragma unroll
    for (int r = 0; r < 8; ++r) { qacc[r][0] = 0.f; qacc[r][1] = 0.f; }
    #pragma unroll 4
    for (int d0 = 0; d0 < DD; d0 += 4) {
      float4 w0 = *(const float4*)&s_A[cl * SW + d0];
      float4 w1 = *(const float4*)&s_A[(cl + 64) * SW + d0];
      #pragma unroll
      for (int r = 0; r < 8; ++r) {
        float4 o = *(const float4*)&s_oa[(ig * 8 + r) * SOA + d0];
        qacc[r][0] += o.x * w0.x + o.y * w0.y + o.z * w0.z + o.w * w0.w;
        qacc[r][1] += o.x * w1.x + o.y * w1.y + o.z * w1.z + o.w * w1.w;
      }
    }
  }
  __syncthreads();   // all Wq reads complete before aliasing s_q over it
  #pragma unroll
  for (int r = 0; r < 8; ++r) {
    s_q[(ig * 8 + r) * SKQ + cl]      = qacc[r][0];
    s_q[(ig * 8 + r) * SKQ + cl + 64] = qacc[r][1];
  }
  __syncthreads();

  // ---------- phase 3: scores + sigmoid ----------
  {
    const int j0 = tid & 31;           // j in {j0, j0+32}
    const int i0 = (tid >> 5) * 4;     // 4 i rows
    float sc[4][2];
    #pragma unroll
    for (int r = 0; r < 4; ++r) { sc[r][0] = 0.f; sc[r][1] = 0.f; }
    #pragma unroll 4
    for (int d0 = 0; d0 < DKD; d0 += 4) {
      float4 q0 = *(const float4*)&s_q[j0 * SKQ + d0];
      float4 q1 = *(const float4*)&s_q[(j0 + 32) * SKQ + d0];
      #pragma unroll
      for (int r = 0; r < 4; ++r) {
        float4 kv = *(const float4*)&s_k[(i0 + r) * SKQ + d0];
        sc[r][0] += kv.x * q0.x + kv.y * q0.y + kv.z * q0.z + kv.w * q0.w;
        sc[r][1] += kv.x * q1.x + kv.y * q1.y + kv.z * q1.z + kv.w * q1.w;
      }
    }
    #pragma unroll
    for (int r = 0; r < 4; ++r) {
      float w0 = 1.0f / (1.0f + __expf(-sc[r][0] * 0.08838834764831845f));
      float w1 = 1.0f / (1.0f + __expf(-sc[r][1] * 0.08838834764831845f));
      s_w[(i0 + r) * SWW + j0]      = w0;
      s_w[(i0 + r) * SWW + j0 + 32] = w1;
    }
  }
  __syncthreads();

  if (tid < 64) {
    float a = 0.f;
    for (int j = 0; j < NN; ++j) a += s_w[tid * SWW + j] * s_vas[j];
    s_sv[tid] = a;
  }
  __syncthreads();

  // ---------- phase 4: write value rows (out) and w (ws) ----------
  float* val_out = out + (size_t)b * NN * NN;
  for (int x = tid; x < NN * NN; x += 512) {
    const int m = x & 63, i = x >> 6;
    val_out[x] = s_ve[i] + (s_sv[i] + s_w[i * SWW + m] * s_dv[m]) * (1.0f / 64.0f);
  }
  float* w_ws = ws + (size_t)b * NN * NN;
  for (int x = tid; x < NN * NN; x += 512) {
    const int j = x & 63, i = x >> 6;
    w_ws[x] = s_w[i * SWW + j];
  }
}

// Broadcast w[b,i,:] (64 f32, read from compact 2 MB ws — L2/LLC resident)
// to 64 m-planes of weights5. Pure coalesced float4 streaming stores.
__global__ __launch_bounds__(256, 8) void critic_c(
    const float* __restrict__ ws, float* __restrict__ out)
{
  const int bid = blockIdx.x;            // bid = b*64 + i
  const int t = threadIdx.x;
  const float4 v = ((const float4*)(ws + (size_t)bid * 64))[t & 15];
  float4* plane = (float4*)(out + (size_t)BB * NN * NN + (size_t)bid * (NN * NN));
  plane[t]       = v;
  plane[t + 256] = v;
  plane[t + 512] = v;
  plane[t + 768] = v;
}

extern "C" void kernel_launch(void* const* d_in, const int* in_sizes, int n_in,
                              void* d_out, int out_size, void* d_ws, size_t ws_size,
                              hipStream_t stream) {
  (void)in_sizes; (void)n_in; (void)out_size; (void)ws_size;
  const float* obs  = (const float*)d_in[0];
  const float* pol  = (const float*)d_in[1];
  const float* act  = (const float*)d_in[2];
  const float* Wk   = (const float*)d_in[3];
  const float* Wq   = (const float*)d_in[4];
  const float* Wv   = (const float*)d_in[5];
  const float* Wenc = (const float*)d_in[6];
  const float* Wfin = (const float*)d_in[7];
  float* out = (float*)d_out;
  float* ws  = (float*)d_ws;
  hipLaunchKernelGGL(critic_a, dim3(BB), dim3(512), 0, stream,
                     obs, pol, act, Wk, Wq, Wv, Wenc, Wfin, out, ws);
  hipLaunchKernelGGL(critic_c, dim3(BB * NN), dim3(256), 0, stream, ws, out);
}

// Round 6
// 193.152 us; speedup vs baseline: 1.5573x; 1.0093x over previous
//
#include <hip/hip_runtime.h>
#include <stdint.h>

// CriticNetwork (passing since R3):
//   value[b,i,m] = ve[i] + (sv[i] + w[i,m]*dv[m]) / 64
//   weights5[b,i,m,j] = w[b,i,j]                      (broadcast over m)
// w = sigmoid(K_b Q_b^T / sqrt(128)), K/Q = oa @ Wk^T / Wq^T
// u = Wv^T wf2, g = Wenc^T wf1, vas[j]=oa[j].u, dv[m]=(pol-act)[m].u[128:],
// ve[i]=obs[i].g, sv[i]=sum_j w[i,j] vas[j].
// R4 post-mortem: dur includes ~85us harness poison fill; critic_a was ~85us
// latency-bound (128 blocks, 1 blk/CU, 9 serial phases). This round: 2-kernel
// split with real parallelism; plane broadcast fused into the scores kernel.
// R5 fix: __builtin_nontemporal_store needs a native vector type, not float4.

#define BB 128
#define NN 64
#define OBSD 128
#define ACTD 16
#define DD 144
#define DKD 128

typedef float f32x4 __attribute__((ext_vector_type(4)));

// ws layout (floats): K[b][i][c] at b*8192; QT[b][c][i] at WS_QT + b*8192;
// vas/ve/dv at WS_VAS/WS_VE/WS_DV + b*64. Total ~8.5 MB (ws is ~400 MB).
#define WS_QT  1048576
#define WS_VAS 2097152
#define WS_VE  (WS_VAS + 8192)
#define WS_DV  (WS_VAS + 16384)

// ---------------- kernel 1: K,Q GEMMs + per-row scalars ----------------
// grid 256: bid = b*2 + half. half0: K + u/g/vas/ve/dv. half1: Q (transposed).
__global__ __launch_bounds__(512, 2) void critic_kq(
    const float* __restrict__ obs, const float* __restrict__ pol, const float* __restrict__ act,
    const float* __restrict__ Wk, const float* __restrict__ Wq, const float* __restrict__ Wv,
    const float* __restrict__ Wenc, const float* __restrict__ Wfin,
    float* __restrict__ ws)
{
  __shared__ __align__(16) float s_oa[NN][148];   // 37.9 KB
  __shared__ __align__(16) float s_W[DKD][148];   // 75.8 KB
  __shared__ float s_dpa[NN][ACTD];
  __shared__ float s_u[DD];
  __shared__ float s_g[OBSD];

  const int tid = threadIdx.x;
  const int b = blockIdx.x >> 1;
  const int half = blockIdx.x & 1;

  // stage oa (obs||act)
  {
    const float4* obs4 = (const float4*)(obs + (size_t)b * NN * OBSD);
    for (int idx = tid; idx < NN * OBSD / 4; idx += 512) {
      int i = idx >> 5, d0 = (idx & 31) * 4;
      *(float4*)&s_oa[i][d0] = obs4[idx];
    }
    const float4* act4 = (const float4*)(act + (size_t)b * NN * ACTD);
    const float4* pol4 = (const float4*)(pol + (size_t)b * NN * ACTD);
    for (int idx = tid; idx < NN * ACTD / 4; idx += 512) {
      float4 a = act4[idx];
      int i = idx >> 2, t0 = (idx & 3) * 4;
      *(float4*)&s_oa[i][OBSD + t0] = a;
      if (half == 0) {
        float4 p = pol4[idx];
        s_dpa[i][t0 + 0] = p.x - a.x; s_dpa[i][t0 + 1] = p.y - a.y;
        s_dpa[i][t0 + 2] = p.z - a.z; s_dpa[i][t0 + 3] = p.w - a.w;
      }
    }
  }
  // stage W (Wk or Wq), 128x144
  {
    const float4* W4 = (const float4*)(half ? Wq : Wk);
    for (int idx = tid; idx < DKD * DD / 4; idx += 512) {
      int row = idx / 36, col = (idx - row * 36) * 4;
      *(float4*)&s_W[row][col] = W4[idx];
    }
  }
  // u,g (half-0 only): 8 independent accumulators to pipeline L2 loads
  if (half == 0) {
    if (tid < DD) {
      float a0=0.f,a1=0.f,a2=0.f,a3=0.f,a4=0.f,a5=0.f,a6=0.f,a7=0.f;
      for (int c = 0; c < DKD; c += 8) {
        a0 += Wv[(size_t)(c+0)*DD + tid] * Wfin[OBSD + c + 0];
        a1 += Wv[(size_t)(c+1)*DD + tid] * Wfin[OBSD + c + 1];
        a2 += Wv[(size_t)(c+2)*DD + tid] * Wfin[OBSD + c + 2];
        a3 += Wv[(size_t)(c+3)*DD + tid] * Wfin[OBSD + c + 3];
        a4 += Wv[(size_t)(c+4)*DD + tid] * Wfin[OBSD + c + 4];
        a5 += Wv[(size_t)(c+5)*DD + tid] * Wfin[OBSD + c + 5];
        a6 += Wv[(size_t)(c+6)*DD + tid] * Wfin[OBSD + c + 6];
        a7 += Wv[(size_t)(c+7)*DD + tid] * Wfin[OBSD + c + 7];
      }
      s_u[tid] = ((a0+a1)+(a2+a3)) + ((a4+a5)+(a6+a7));
    } else if (tid < DD + OBSD) {
      const int d = tid - DD;
      float a0=0.f,a1=0.f,a2=0.f,a3=0.f,a4=0.f,a5=0.f,a6=0.f,a7=0.f;
      for (int c = 0; c < 128; c += 8) {
        a0 += Wenc[(size_t)(c+0)*OBSD + d] * Wfin[c + 0];
        a1 += Wenc[(size_t)(c+1)*OBSD + d] * Wfin[c + 1];
        a2 += Wenc[(size_t)(c+2)*OBSD + d] * Wfin[c + 2];
        a3 += Wenc[(size_t)(c+3)*OBSD + d] * Wfin[c + 3];
        a4 += Wenc[(size_t)(c+4)*OBSD + d] * Wfin[c + 4];
        a5 += Wenc[(size_t)(c+5)*OBSD + d] * Wfin[c + 5];
        a6 += Wenc[(size_t)(c+6)*OBSD + d] * Wfin[c + 6];
        a7 += Wenc[(size_t)(c+7)*OBSD + d] * Wfin[c + 7];
      }
      s_g[d] = ((a0+a1)+(a2+a3)) + ((a4+a5)+(a6+a7));
    }
  }
  __syncthreads();

  // GEMM: lanes = col c (cl, cl+64); wave ig handles rows ig*8..+7.
  const int cl = tid & 63;
  const int ig = tid >> 6;
  float acc0[8], acc1[8];
  #pragma unroll
  for (int r = 0; r < 8; ++r) { acc0[r] = 0.f; acc1[r] = 0.f; }
  #pragma unroll 4
  for (int d0 = 0; d0 < DD; d0 += 4) {
    float4 w0 = *(const float4*)&s_W[cl][d0];
    float4 w1 = *(const float4*)&s_W[cl + 64][d0];
    #pragma unroll
    for (int r = 0; r < 8; ++r) {
      float4 o = *(const float4*)&s_oa[ig * 8 + r][d0];   // wave-uniform: broadcast
      acc0[r] += o.x * w0.x + o.y * w0.y + o.z * w0.z + o.w * w0.w;
      acc1[r] += o.x * w1.x + o.y * w1.y + o.z * w1.z + o.w * w1.w;
    }
  }

  if (half == 0) {
    float* kb = ws + (size_t)b * 8192;            // K[i][c], coalesced
    #pragma unroll
    for (int r = 0; r < 8; ++r) {
      kb[(ig * 8 + r) * 128 + cl]      = acc0[r];
      kb[(ig * 8 + r) * 128 + cl + 64] = acc1[r];
    }
    // scalars (read s_oa/s_u/s_g/s_dpa — all stable since barrier)
    if (tid < 64) {
      float a = 0.f;
      for (int d = 0; d < DD; ++d) a += s_oa[tid][d] * s_u[d];
      ws[WS_VAS + b * 64 + tid] = a;
    } else if (tid < 128) {
      const int i = tid - 64;
      float a = 0.f;
      for (int d = 0; d < OBSD; ++d) a += s_oa[i][d] * s_g[d];
      ws[WS_VE + b * 64 + i] = a;
    } else if (tid < 192) {
      const int i = tid - 128;
      float a = 0.f;
      #pragma unroll
      for (int t = 0; t < ACTD; ++t) a += s_dpa[i][t] * s_u[OBSD + t];
      ws[WS_DV + b * 64 + i] = a;
    }
  } else {
    float* qb = ws + WS_QT + (size_t)b * 8192;    // QT[c][i], scattered (4 MB, cheap)
    #pragma unroll
    for (int r = 0; r < 8; ++r) {
      qb[cl * 64 + ig * 8 + r]        = acc0[r];
      qb[(cl + 64) * 64 + ig * 8 + r] = acc1[r];
    }
  }
}

// -------- kernel 2: scores + sigmoid + sv + value + fused plane broadcast --------
// grid 512: bid = b*4 + ig; 16 i-rows per block; 2 blocks/CU (46 KB LDS).
__global__ __launch_bounds__(256, 2) void critic_sw(
    const float* __restrict__ ws, float* __restrict__ out)
{
  __shared__ __align__(16) float s_qT[DKD][64];   // 32 KB, [c][j]: conflict-free j-lanes
  __shared__ __align__(16) float s_k[16][132];    // 8.4 KB, wave-uniform reads
  __shared__ __align__(16) float s_w[16][68];     // 4.3 KB
  __shared__ float s_vas[64], s_dv[64], s_ve[16], s_sv[16];

  const int t = threadIdx.x;
  const int b = blockIdx.x >> 2;
  const int i0 = (blockIdx.x & 3) * 16;

  // stage QT (coalesced read, conflict-free LDS write: 16 thr cover one c-row)
  {
    const float4* qt4 = (const float4*)(ws + WS_QT + (size_t)b * 8192);
    for (int idx = t; idx < 2048; idx += 256) {
      int c = idx >> 4, i4 = (idx & 15) * 4;
      *(float4*)&s_qT[c][i4] = qt4[idx];
    }
    const float4* k4 = (const float4*)(ws + (size_t)b * 8192 + (size_t)i0 * 128);
    for (int idx = t; idx < 512; idx += 256) {
      int r = idx >> 5, c4 = (idx & 31) * 4;
      *(float4*)&s_k[r][c4] = k4[idx];
    }
    if (t < 64)            s_vas[t] = ws[WS_VAS + b * 64 + t];
    else if (t < 128)      s_dv[t - 64] = ws[WS_DV + b * 64 + (t - 64)];
    else if (t < 144)      s_ve[t - 128] = ws[WS_VE + b * 64 + i0 + (t - 128)];
  }
  __syncthreads();

  // scores: wave wv -> rows wv*4..+3; lane j. sc[r] = K[i].Q[j]
  {
    const int wv = t >> 6, j = t & 63;
    float sc0 = 0.f, sc1 = 0.f, sc2 = 0.f, sc3 = 0.f;
    #pragma unroll 4
    for (int d0 = 0; d0 < DKD; d0 += 4) {
      float q0 = s_qT[d0 + 0][j], q1 = s_qT[d0 + 1][j];
      float q2 = s_qT[d0 + 2][j], q3 = s_qT[d0 + 3][j];
      float4 k0 = *(const float4*)&s_k[wv * 4 + 0][d0];
      float4 k1 = *(const float4*)&s_k[wv * 4 + 1][d0];
      float4 k2 = *(const float4*)&s_k[wv * 4 + 2][d0];
      float4 k3 = *(const float4*)&s_k[wv * 4 + 3][d0];
      sc0 += k0.x * q0 + k0.y * q1 + k0.z * q2 + k0.w * q3;
      sc1 += k1.x * q0 + k1.y * q1 + k1.z * q2 + k1.w * q3;
      sc2 += k2.x * q0 + k2.y * q1 + k2.z * q2 + k2.w * q3;
      sc3 += k3.x * q0 + k3.y * q1 + k3.z * q2 + k3.w * q3;
    }
    const float kk = 0.08838834764831845f;  // 1/sqrt(128)
    s_w[wv * 4 + 0][j] = 1.0f / (1.0f + __expf(-sc0 * kk));
    s_w[wv * 4 + 1][j] = 1.0f / (1.0f + __expf(-sc1 * kk));
    s_w[wv * 4 + 2][j] = 1.0f / (1.0f + __expf(-sc2 * kk));
    s_w[wv * 4 + 3][j] = 1.0f / (1.0f + __expf(-sc3 * kk));
  }
  __syncthreads();

  if (t < 16) {
    float a = 0.f;
    for (int j = 0; j < 64; ++j) a += s_w[t][j] * s_vas[j];
    s_sv[t] = a;
  }
  __syncthreads();

  // value rows [b, i0+r, m]
  {
    const int r = t >> 4, m4 = (t & 15) * 4;
    float4 v;
    v.x = s_ve[r] + (s_sv[r] + s_w[r][m4 + 0] * s_dv[m4 + 0]) * (1.0f / 64.0f);
    v.y = s_ve[r] + (s_sv[r] + s_w[r][m4 + 1] * s_dv[m4 + 1]) * (1.0f / 64.0f);
    v.z = s_ve[r] + (s_sv[r] + s_w[r][m4 + 2] * s_dv[m4 + 2]) * (1.0f / 64.0f);
    v.w = s_ve[r] + (s_sv[r] + s_w[r][m4 + 3] * s_dv[m4 + 3]) * (1.0f / 64.0f);
    *(float4*)(out + ((size_t)(b * 64 + i0 + r) * 64 + m4)) = v;
  }

  // fused broadcast: 16 planes x 16 KB, nontemporal streaming stores
  float* w5 = out + (size_t)BB * NN * NN;
  #pragma unroll 4
  for (int r = 0; r < 16; ++r) {
    const f32x4 wv4 = *(const f32x4*)&s_w[r][(t & 15) * 4];
    f32x4* p4 = (f32x4*)(w5 + ((size_t)(b * 64 + i0 + r) << 12));
    __builtin_nontemporal_store(wv4, &p4[t]);
    __builtin_nontemporal_store(wv4, &p4[t + 256]);
    __builtin_nontemporal_store(wv4, &p4[t + 512]);
    __builtin_nontemporal_store(wv4, &p4[t + 768]);
  }
}

extern "C" void kernel_launch(void* const* d_in, const int* in_sizes, int n_in,
                              void* d_out, int out_size, void* d_ws, size_t ws_size,
                              hipStream_t stream) {
  (void)in_sizes; (void)n_in; (void)out_size; (void)ws_size;
  const float* obs  = (const float*)d_in[0];
  const float* pol  = (const float*)d_in[1];
  const float* act  = (const float*)d_in[2];
  const float* Wk   = (const float*)d_in[3];
  const float* Wq   = (const float*)d_in[4];
  const float* Wv   = (const float*)d_in[5];
  const float* Wenc = (const float*)d_in[6];
  const float* Wfin = (const float*)d_in[7];
  float* out = (float*)d_out;
  float* ws  = (float*)d_ws;
  hipLaunchKernelGGL(critic_kq, dim3(BB * 2), dim3(512), 0, stream,
                     obs, pol, act, Wk, Wq, Wv, Wenc, Wfin, ws);
  hipLaunchKernelGGL(critic_sw, dim3(BB * 4), dim3(256), 0, stream, ws, out);
}

// Round 7
// 179.428 us; speedup vs baseline: 1.6764x; 1.0765x over previous
//
#include <hip/hip_runtime.h>
#include <stdint.h>

// CriticNetwork (passing since R3):
//   value[b,i,m] = ve[i] + (sv[i] + w[i,m]*dv[m]) / 64
//   weights5[b,i,m,j] = w[b,i,j]                      (broadcast over m)
// w = sigmoid(K_b Q_b^T / sqrt(128)), K/Q = oa @ Wk^T / Wq^T
// u = Wv^T wf2, g = Wenc^T wf1, vas[j]=oa[j].u, dv[m]=(pol-act)[m].u[128:],
// ve[i]=obs[i].g, sv[i]=sum_j w[i,j] vas[j].
// R6 forensics: dur = fill(88, harness poison of out+ws, fixed) + kq + sw;
// kq+sw ~= 105us, sw ~= 22-25 (write-floor) => kq ~= 80us (1 blk/CU, LDS
// conflicts, f32 VALU GEMM). This round: kq rewritten as bf16 MFMA
// (16x16x32, K padded 144->160), LDS 70 KB -> 2 blk/CU. Numerics: bf16
// rounding on K/Q adds ~2e-3 to w; threshold 0.0234.

#define BB 128
#define NN 64
#define OBSD 128
#define ACTD 16
#define DD 144
#define DKD 128
#define RS 168   // LDS row stride in bf16 for A/B tiles (pad vs 160: bank spread)

typedef float f32x4 __attribute__((ext_vector_type(4)));
typedef short bf16x8 __attribute__((ext_vector_type(8)));

// ws layout (floats): K[b][i][c] at b*8192; QT[b][c][i] at WS_QT + b*8192;
// vas/ve/dv at WS_VAS/WS_VE/WS_DV + b*64.
#define WS_QT  1048576
#define WS_VAS 2097152
#define WS_VE  (WS_VAS + 8192)
#define WS_DV  (WS_VAS + 16384)

__device__ __forceinline__ unsigned int pack_bf2(float x, float y) {
  unsigned a = __float_as_uint(x), b = __float_as_uint(y);
  a = (a + 0x7fffu + ((a >> 16) & 1u)) >> 16;
  b = (b + 0x7fffu + ((b >> 16) & 1u)) >> 16;
  return a | (b << 16);
}
__device__ __forceinline__ float bf2f(unsigned short s) {
  return __uint_as_float(((unsigned)s) << 16);
}

// ---------------- kernel 1: K,Q via bf16 MFMA + per-row scalars ----------------
// grid 256: bid = b*2 + half. half0: K (+ u/g/vas/ve/dv). half1: Q -> QT.
__global__ __launch_bounds__(512, 2) void critic_kq(
    const float* __restrict__ obs, const float* __restrict__ pol, const float* __restrict__ act,
    const float* __restrict__ Wk, const float* __restrict__ Wq, const float* __restrict__ Wv,
    const float* __restrict__ Wenc, const float* __restrict__ Wfin,
    float* __restrict__ ws)
{
  __shared__ __align__(16) unsigned short s_A[NN * RS];    // oa bf16, 21.5 KB
  __shared__ __align__(16) unsigned short s_B[DKD * RS];   // W  bf16, 43 KB
  __shared__ float s_dpa[NN][ACTD];
  __shared__ float s_u[DD];
  __shared__ float s_g[OBSD];

  const int tid = threadIdx.x;
  const int b = blockIdx.x >> 1;
  const int half = blockIdx.x & 1;

  // ---- stage A = oa[b] (64 x 144 f32 -> bf16), pad cols 144..159 = 0
  {
    const float4* obs4 = (const float4*)(obs + (size_t)b * NN * OBSD);
    for (int idx = tid; idx < 2048; idx += 512) {          // 64 rows x 32 groups
      float4 v = obs4[idx];
      int row = idx >> 5, c4 = (idx & 31) * 4;
      *(uint2*)&s_A[row * RS + c4] = make_uint2(pack_bf2(v.x, v.y), pack_bf2(v.z, v.w));
    }
    const float4* act4 = (const float4*)(act + (size_t)b * NN * ACTD);
    const float4* pol4 = (const float4*)(pol + (size_t)b * NN * ACTD);
    for (int idx = tid; idx < 256; idx += 512) {           // 64 rows x 4 groups
      float4 a = act4[idx];
      int row = idx >> 2, c4 = OBSD + (idx & 3) * 4;
      *(uint2*)&s_A[row * RS + c4] = make_uint2(pack_bf2(a.x, a.y), pack_bf2(a.z, a.w));
      if (half == 0) {
        float4 p = pol4[idx];
        int t0 = (idx & 3) * 4;
        s_dpa[row][t0 + 0] = p.x - a.x; s_dpa[row][t0 + 1] = p.y - a.y;
        s_dpa[row][t0 + 2] = p.z - a.z; s_dpa[row][t0 + 3] = p.w - a.w;
      }
    }
    for (int idx = tid; idx < 256; idx += 512) {           // zero pad 144..159
      int row = idx >> 2, c4 = DD + (idx & 3) * 4;
      *(uint2*)&s_A[row * RS + c4] = make_uint2(0u, 0u);
    }
  }
  // ---- stage B = W(half) (128 x 144 -> bf16) + zero pad
  {
    const float4* W4 = (const float4*)(half ? Wq : Wk);
    for (int idx = tid; idx < 4096; idx += 512) {          // 128 rows x 32 groups
      int row = idx >> 5, g = idx & 31;
      float4 v = W4[row * 36 + g];
      *(uint2*)&s_B[row * RS + g * 4] = make_uint2(pack_bf2(v.x, v.y), pack_bf2(v.z, v.w));
    }
    for (int idx = tid; idx < 512; idx += 512) {           // 128 rows x 4 groups tail
      int row = idx >> 2, g = idx & 3;
      float4 v = W4[row * 36 + 32 + g];
      *(uint2*)&s_B[row * RS + OBSD + g * 4] = make_uint2(pack_bf2(v.x, v.y), pack_bf2(v.z, v.w));
    }
    for (int idx = tid; idx < 512; idx += 512) {           // zero pad
      int row = idx >> 2, c4 = DD + (idx & 3) * 4;
      *(uint2*)&s_B[row * RS + c4] = make_uint2(0u, 0u);
    }
  }
  // ---- u, g (half0): coalesced L2 loads, 8-way ILP
  if (half == 0) {
    if (tid < DD) {
      float a0=0.f,a1=0.f,a2=0.f,a3=0.f,a4=0.f,a5=0.f,a6=0.f,a7=0.f;
      for (int c = 0; c < DKD; c += 8) {
        a0 += Wv[(size_t)(c+0)*DD + tid] * Wfin[OBSD + c + 0];
        a1 += Wv[(size_t)(c+1)*DD + tid] * Wfin[OBSD + c + 1];
        a2 += Wv[(size_t)(c+2)*DD + tid] * Wfin[OBSD + c + 2];
        a3 += Wv[(size_t)(c+3)*DD + tid] * Wfin[OBSD + c + 3];
        a4 += Wv[(size_t)(c+4)*DD + tid] * Wfin[OBSD + c + 4];
        a5 += Wv[(size_t)(c+5)*DD + tid] * Wfin[OBSD + c + 5];
        a6 += Wv[(size_t)(c+6)*DD + tid] * Wfin[OBSD + c + 6];
        a7 += Wv[(size_t)(c+7)*DD + tid] * Wfin[OBSD + c + 7];
      }
      s_u[tid] = ((a0+a1)+(a2+a3)) + ((a4+a5)+(a6+a7));
    } else if (tid < DD + OBSD) {
      const int d = tid - DD;
      float a0=0.f,a1=0.f,a2=0.f,a3=0.f,a4=0.f,a5=0.f,a6=0.f,a7=0.f;
      for (int c = 0; c < 128; c += 8) {
        a0 += Wenc[(size_t)(c+0)*OBSD + d] * Wfin[c + 0];
        a1 += Wenc[(size_t)(c+1)*OBSD + d] * Wfin[c + 1];
        a2 += Wenc[(size_t)(c+2)*OBSD + d] * Wfin[c + 2];
        a3 += Wenc[(size_t)(c+3)*OBSD + d] * Wfin[c + 3];
        a4 += Wenc[(size_t)(c+4)*OBSD + d] * Wfin[c + 4];
        a5 += Wenc[(size_t)(c+5)*OBSD + d] * Wfin[c + 5];
        a6 += Wenc[(size_t)(c+6)*OBSD + d] * Wfin[c + 6];
        a7 += Wenc[(size_t)(c+7)*OBSD + d] * Wfin[c + 7];
      }
      s_g[d] = ((a0+a1)+(a2+a3)) + ((a4+a5)+(a6+a7));
    }
  }
  __syncthreads();

  // ---- MFMA: wave w -> i-tile (w&3)*16, N-tiles (w>>2)*4 .. +3
  {
    const int wv = tid >> 6, lane = tid & 63;
    const int i0 = (wv & 3) * 16;
    const int n0 = (wv >> 2) * 4;
    const int m = lane & 15, q = lane >> 4;
    f32x4 acc[4];
    #pragma unroll
    for (int t = 0; t < 4; ++t) acc[t] = (f32x4){0.f, 0.f, 0.f, 0.f};
    #pragma unroll
    for (int ks = 0; ks < 5; ++ks) {
      const int koff = ks * 32 + q * 8;
      bf16x8 a = *(const bf16x8*)&s_A[(i0 + m) * RS + koff];
      #pragma unroll
      for (int t = 0; t < 4; ++t) {
        bf16x8 bb = *(const bf16x8*)&s_B[((n0 + t) * 16 + m) * RS + koff];
        acc[t] = __builtin_amdgcn_mfma_f32_16x16x32_bf16(a, bb, acc[t], 0, 0, 0);
      }
    }
    // D[i0 + q*4 + r][ (n0+t)*16 + m ]
    if (half == 0) {
      float* kb = ws + (size_t)b * 8192;
      #pragma unroll
      for (int t = 0; t < 4; ++t)
        #pragma unroll
        for (int r = 0; r < 4; ++r)
          kb[(i0 + q * 4 + r) * 128 + (n0 + t) * 16 + m] = acc[t][r];
    } else {
      float* qb = ws + WS_QT + (size_t)b * 8192;   // QT[c][i]
      #pragma unroll
      for (int t = 0; t < 4; ++t)
        *(f32x4*)&qb[((n0 + t) * 16 + m) * 64 + i0 + q * 4] = acc[t];
    }
  }

  // ---- per-row scalars (half0): from bf16 s_A (err ~1e-3, budget 0.023)
  if (half == 0) {
    if (tid < 64) {
      float a = 0.f;
      for (int d = 0; d < DD; ++d) a += bf2f(s_A[tid * RS + d]) * s_u[d];
      ws[WS_VAS + b * 64 + tid] = a;
    } else if (tid < 128) {
      const int i = tid - 64;
      float a = 0.f;
      for (int d = 0; d < OBSD; ++d) a += bf2f(s_A[i * RS + d]) * s_g[d];
      ws[WS_VE + b * 64 + i] = a;
    } else if (tid < 192) {
      const int i = tid - 128;
      float a = 0.f;
      #pragma unroll
      for (int t = 0; t < ACTD; ++t) a += s_dpa[i][t] * s_u[OBSD + t];
      ws[WS_DV + b * 64 + i] = a;
    }
  }
}

// -------- kernel 2: scores + sigmoid + sv + value + fused plane broadcast --------
// grid 512: bid = b*4 + ig; 16 i-rows per block; 2 blocks/CU (46 KB LDS).
__global__ __launch_bounds__(256, 2) void critic_sw(
    const float* __restrict__ ws, float* __restrict__ out)
{
  __shared__ __align__(16) float s_qT[DKD][64];   // [c][j]: conflict-free j-lanes
  __shared__ __align__(16) float s_k[16][132];
  __shared__ __align__(16) float s_w[16][68];
  __shared__ float s_vas[64], s_dv[64], s_ve[16], s_sv[16];

  const int t = threadIdx.x;
  const int b = blockIdx.x >> 2;
  const int i0 = (blockIdx.x & 3) * 16;

  {
    const float4* qt4 = (const float4*)(ws + WS_QT + (size_t)b * 8192);
    for (int idx = t; idx < 2048; idx += 256) {
      int c = idx >> 4, i4 = (idx & 15) * 4;
      *(float4*)&s_qT[c][i4] = qt4[idx];
    }
    const float4* k4 = (const float4*)(ws + (size_t)b * 8192 + (size_t)i0 * 128);
    for (int idx = t; idx < 512; idx += 256) {
      int r = idx >> 5, c4 = (idx & 31) * 4;
      *(float4*)&s_k[r][c4] = k4[idx];
    }
    if (t < 64)            s_vas[t] = ws[WS_VAS + b * 64 + t];
    else if (t < 128)      s_dv[t - 64] = ws[WS_DV + b * 64 + (t - 64)];
    else if (t < 144)      s_ve[t - 128] = ws[WS_VE + b * 64 + i0 + (t - 128)];
  }
  __syncthreads();

  {
    const int wv = t >> 6, j = t & 63;
    float sc0 = 0.f, sc1 = 0.f, sc2 = 0.f, sc3 = 0.f;
    #pragma unroll 4
    for (int d0 = 0; d0 < DKD; d0 += 4) {
      float q0 = s_qT[d0 + 0][j], q1 = s_qT[d0 + 1][j];
      float q2 = s_qT[d0 + 2][j], q3 = s_qT[d0 + 3][j];
      float4 k0 = *(const float4*)&s_k[wv * 4 + 0][d0];
      float4 k1 = *(const float4*)&s_k[wv * 4 + 1][d0];
      float4 k2 = *(const float4*)&s_k[wv * 4 + 2][d0];
      float4 k3 = *(const float4*)&s_k[wv * 4 + 3][d0];
      sc0 += k0.x * q0 + k0.y * q1 + k0.z * q2 + k0.w * q3;
      sc1 += k1.x * q0 + k1.y * q1 + k1.z * q2 + k1.w * q3;
      sc2 += k2.x * q0 + k2.y * q1 + k2.z * q2 + k2.w * q3;
      sc3 += k3.x * q0 + k3.y * q1 + k3.z * q2 + k3.w * q3;
    }
    const float kk = 0.08838834764831845f;  // 1/sqrt(128)
    s_w[wv * 4 + 0][j] = 1.0f / (1.0f + __expf(-sc0 * kk));
    s_w[wv * 4 + 1][j] = 1.0f / (1.0f + __expf(-sc1 * kk));
    s_w[wv * 4 + 2][j] = 1.0f / (1.0f + __expf(-sc2 * kk));
    s_w[wv * 4 + 3][j] = 1.0f / (1.0f + __expf(-sc3 * kk));
  }
  __syncthreads();

  if (t < 16) {
    float a = 0.f;
    for (int j = 0; j < 64; ++j) a += s_w[t][j] * s_vas[j];
    s_sv[t] = a;
  }
  __syncthreads();

  {
    const int r = t >> 4, m4 = (t & 15) * 4;
    float4 v;
    v.x = s_ve[r] + (s_sv[r] + s_w[r][m4 + 0] * s_dv[m4 + 0]) * (1.0f / 64.0f);
    v.y = s_ve[r] + (s_sv[r] + s_w[r][m4 + 1] * s_dv[m4 + 1]) * (1.0f / 64.0f);
    v.z = s_ve[r] + (s_sv[r] + s_w[r][m4 + 2] * s_dv[m4 + 2]) * (1.0f / 64.0f);
    v.w = s_ve[r] + (s_sv[r] + s_w[r][m4 + 3] * s_dv[m4 + 3]) * (1.0f / 64.0f);
    *(float4*)(out + ((size_t)(b * 64 + i0 + r) * 64 + m4)) = v;
  }

  float* w5 = out + (size_t)BB * NN * NN;
  #pragma unroll 4
  for (int r = 0; r < 16; ++r) {
    const f32x4 wv4 = *(const f32x4*)&s_w[r][(t & 15) * 4];
    f32x4* p4 = (f32x4*)(w5 + ((size_t)(b * 64 + i0 + r) << 12));
    __builtin_nontemporal_store(wv4, &p4[t]);
    __builtin_nontemporal_store(wv4, &p4[t + 256]);
    __builtin_nontemporal_store(wv4, &p4[t + 512]);
    __builtin_nontemporal_store(wv4, &p4[t + 768]);
  }
}

extern "C" void kernel_launch(void* const* d_in, const int* in_sizes, int n_in,
                              void* d_out, int out_size, void* d_ws, size_t ws_size,
                              hipStream_t stream) {
  (void)in_sizes; (void)n_in; (void)out_size; (void)ws_size;
  const float* obs  = (const float*)d_in[0];
  const float* pol  = (const float*)d_in[1];
  const float* act  = (const float*)d_in[2];
  const float* Wk   = (const float*)d_in[3];
  const float* Wq   = (const float*)d_in[4];
  const float* Wv   = (const float*)d_in[5];
  const float* Wenc = (const float*)d_in[6];
  const float* Wfin = (const float*)d_in[7];
  float* out = (float*)d_out;
  float* ws  = (float*)d_ws;
  hipLaunchKernelGGL(critic_kq, dim3(BB * 2), dim3(512), 0, stream,
                     obs, pol, act, Wk, Wq, Wv, Wenc, Wfin, ws);
  hipLaunchKernelGGL(critic_sw, dim3(BB * 4), dim3(256), 0, stream, ws, out);
}

// Round 8
// 175.281 us; speedup vs baseline: 1.7161x; 1.0237x over previous
//
#include <hip/hip_runtime.h>
#include <stdint.h>

// CriticNetwork (passing since R3):
//   value[b,i,m] = ve[i] + (sv[i] + w[i,m]*dv[m]) / 64
//   weights5[b,i,m,j] = w[b,i,j]                      (broadcast over m)
// w = sigmoid(K_b Q_b^T / sqrt(128)), K/Q = oa @ Wk^T / Wq^T
// u = Wv^T wf2, g = Wenc^T wf1, vas[j]=oa[j].u, dv[m]=(pol-act)[m].u[128:],
// ve[i]=obs[i].g, sv[i]=sum_j w[i,j] vas[j].
// R7 forensics: dur = fill(86, fixed) + kq(~8) + sw(~85!). sw writes 136 MB
// at only 1.6 TB/s -> nontemporal stores are ~4x slower than regular stores
// on gfx950 (fill: 6.3 TB/s, R4 critic_c regular stores ~5 TB/s). This round:
// plain float4 stores in sw, launch_bounds(256,3).

#define BB 128
#define NN 64
#define OBSD 128
#define ACTD 16
#define DD 144
#define DKD 128
#define RS 168   // LDS row stride in bf16 for A/B tiles

typedef float f32x4 __attribute__((ext_vector_type(4)));
typedef short bf16x8 __attribute__((ext_vector_type(8)));

// ws layout (floats): K[b][i][c] at b*8192; QT[b][c][i] at WS_QT + b*8192;
// vas/ve/dv at WS_VAS/WS_VE/WS_DV + b*64.
#define WS_QT  1048576
#define WS_VAS 2097152
#define WS_VE  (WS_VAS + 8192)
#define WS_DV  (WS_VAS + 16384)

__device__ __forceinline__ unsigned int pack_bf2(float x, float y) {
  unsigned a = __float_as_uint(x), b = __float_as_uint(y);
  a = (a + 0x7fffu + ((a >> 16) & 1u)) >> 16;
  b = (b + 0x7fffu + ((b >> 16) & 1u)) >> 16;
  return a | (b << 16);
}
__device__ __forceinline__ float bf2f(unsigned short s) {
  return __uint_as_float(((unsigned)s) << 16);
}

// ---------------- kernel 1: K,Q via bf16 MFMA + per-row scalars ----------------
// grid 256: bid = b*2 + half. half0: K (+ u/g/vas/ve/dv). half1: Q -> QT.
__global__ __launch_bounds__(512, 2) void critic_kq(
    const float* __restrict__ obs, const float* __restrict__ pol, const float* __restrict__ act,
    const float* __restrict__ Wk, const float* __restrict__ Wq, const float* __restrict__ Wv,
    const float* __restrict__ Wenc, const float* __restrict__ Wfin,
    float* __restrict__ ws)
{
  __shared__ __align__(16) unsigned short s_A[NN * RS];    // oa bf16, 21.5 KB
  __shared__ __align__(16) unsigned short s_B[DKD * RS];   // W  bf16, 43 KB
  __shared__ float s_dpa[NN][ACTD];
  __shared__ float s_u[DD];
  __shared__ float s_g[OBSD];

  const int tid = threadIdx.x;
  const int b = blockIdx.x >> 1;
  const int half = blockIdx.x & 1;

  // ---- stage A = oa[b] (64 x 144 f32 -> bf16), pad cols 144..159 = 0
  {
    const float4* obs4 = (const float4*)(obs + (size_t)b * NN * OBSD);
    for (int idx = tid; idx < 2048; idx += 512) {          // 64 rows x 32 groups
      float4 v = obs4[idx];
      int row = idx >> 5, c4 = (idx & 31) * 4;
      *(uint2*)&s_A[row * RS + c4] = make_uint2(pack_bf2(v.x, v.y), pack_bf2(v.z, v.w));
    }
    const float4* act4 = (const float4*)(act + (size_t)b * NN * ACTD);
    const float4* pol4 = (const float4*)(pol + (size_t)b * NN * ACTD);
    for (int idx = tid; idx < 256; idx += 512) {           // 64 rows x 4 groups
      float4 a = act4[idx];
      int row = idx >> 2, c4 = OBSD + (idx & 3) * 4;
      *(uint2*)&s_A[row * RS + c4] = make_uint2(pack_bf2(a.x, a.y), pack_bf2(a.z, a.w));
      if (half == 0) {
        float4 p = pol4[idx];
        int t0 = (idx & 3) * 4;
        s_dpa[row][t0 + 0] = p.x - a.x; s_dpa[row][t0 + 1] = p.y - a.y;
        s_dpa[row][t0 + 2] = p.z - a.z; s_dpa[row][t0 + 3] = p.w - a.w;
      }
    }
    for (int idx = tid; idx < 256; idx += 512) {           // zero pad 144..159
      int row = idx >> 2, c4 = DD + (idx & 3) * 4;
      *(uint2*)&s_A[row * RS + c4] = make_uint2(0u, 0u);
    }
  }
  // ---- stage B = W(half) (128 x 144 -> bf16) + zero pad
  {
    const float4* W4 = (const float4*)(half ? Wq : Wk);
    for (int idx = tid; idx < 4096; idx += 512) {          // 128 rows x 32 groups
      int row = idx >> 5, g = idx & 31;
      float4 v = W4[row * 36 + g];
      *(uint2*)&s_B[row * RS + g * 4] = make_uint2(pack_bf2(v.x, v.y), pack_bf2(v.z, v.w));
    }
    for (int idx = tid; idx < 512; idx += 512) {           // 128 rows x 4 groups tail
      int row = idx >> 2, g = idx & 3;
      float4 v = W4[row * 36 + 32 + g];
      *(uint2*)&s_B[row * RS + OBSD + g * 4] = make_uint2(pack_bf2(v.x, v.y), pack_bf2(v.z, v.w));
    }
    for (int idx = tid; idx < 512; idx += 512) {           // zero pad
      int row = idx >> 2, c4 = DD + (idx & 3) * 4;
      *(uint2*)&s_B[row * RS + c4] = make_uint2(0u, 0u);
    }
  }
  // ---- u, g (half0): coalesced L2 loads, 8-way ILP
  if (half == 0) {
    if (tid < DD) {
      float a0=0.f,a1=0.f,a2=0.f,a3=0.f,a4=0.f,a5=0.f,a6=0.f,a7=0.f;
      for (int c = 0; c < DKD; c += 8) {
        a0 += Wv[(size_t)(c+0)*DD + tid] * Wfin[OBSD + c + 0];
        a1 += Wv[(size_t)(c+1)*DD + tid] * Wfin[OBSD + c + 1];
        a2 += Wv[(size_t)(c+2)*DD + tid] * Wfin[OBSD + c + 2];
        a3 += Wv[(size_t)(c+3)*DD + tid] * Wfin[OBSD + c + 3];
        a4 += Wv[(size_t)(c+4)*DD + tid] * Wfin[OBSD + c + 4];
        a5 += Wv[(size_t)(c+5)*DD + tid] * Wfin[OBSD + c + 5];
        a6 += Wv[(size_t)(c+6)*DD + tid] * Wfin[OBSD + c + 6];
        a7 += Wv[(size_t)(c+7)*DD + tid] * Wfin[OBSD + c + 7];
      }
      s_u[tid] = ((a0+a1)+(a2+a3)) + ((a4+a5)+(a6+a7));
    } else if (tid < DD + OBSD) {
      const int d = tid - DD;
      float a0=0.f,a1=0.f,a2=0.f,a3=0.f,a4=0.f,a5=0.f,a6=0.f,a7=0.f;
      for (int c = 0; c < 128; c += 8) {
        a0 += Wenc[(size_t)(c+0)*OBSD + d] * Wfin[c + 0];
        a1 += Wenc[(size_t)(c+1)*OBSD + d] * Wfin[c + 1];
        a2 += Wenc[(size_t)(c+2)*OBSD + d] * Wfin[c + 2];
        a3 += Wenc[(size_t)(c+3)*OBSD + d] * Wfin[c + 3];
        a4 += Wenc[(size_t)(c+4)*OBSD + d] * Wfin[c + 4];
        a5 += Wenc[(size_t)(c+5)*OBSD + d] * Wfin[c + 5];
        a6 += Wenc[(size_t)(c+6)*OBSD + d] * Wfin[c + 6];
        a7 += Wenc[(size_t)(c+7)*OBSD + d] * Wfin[c + 7];
      }
      s_g[d] = ((a0+a1)+(a2+a3)) + ((a4+a5)+(a6+a7));
    }
  }
  __syncthreads();

  // ---- MFMA: wave w -> i-tile (w&3)*16, N-tiles (w>>2)*4 .. +3
  {
    const int wv = tid >> 6, lane = tid & 63;
    const int i0 = (wv & 3) * 16;
    const int n0 = (wv >> 2) * 4;
    const int m = lane & 15, q = lane >> 4;
    f32x4 acc[4];
    #pragma unroll
    for (int t = 0; t < 4; ++t) acc[t] = (f32x4){0.f, 0.f, 0.f, 0.f};
    #pragma unroll
    for (int ks = 0; ks < 5; ++ks) {
      const int koff = ks * 32 + q * 8;
      bf16x8 a = *(const bf16x8*)&s_A[(i0 + m) * RS + koff];
      #pragma unroll
      for (int t = 0; t < 4; ++t) {
        bf16x8 bb = *(const bf16x8*)&s_B[((n0 + t) * 16 + m) * RS + koff];
        acc[t] = __builtin_amdgcn_mfma_f32_16x16x32_bf16(a, bb, acc[t], 0, 0, 0);
      }
    }
    // D[i0 + q*4 + r][ (n0+t)*16 + m ]
    if (half == 0) {
      float* kb = ws + (size_t)b * 8192;
      #pragma unroll
      for (int t = 0; t < 4; ++t)
        #pragma unroll
        for (int r = 0; r < 4; ++r)
          kb[(i0 + q * 4 + r) * 128 + (n0 + t) * 16 + m] = acc[t][r];
    } else {
      float* qb = ws + WS_QT + (size_t)b * 8192;   // QT[c][i]
      #pragma unroll
      for (int t = 0; t < 4; ++t)
        *(f32x4*)&qb[((n0 + t) * 16 + m) * 64 + i0 + q * 4] = acc[t];
    }
  }

  // ---- per-row scalars (half0): from bf16 s_A (err ~1e-3, budget 0.023)
  if (half == 0) {
    if (tid < 64) {
      float a = 0.f;
      for (int d = 0; d < DD; ++d) a += bf2f(s_A[tid * RS + d]) * s_u[d];
      ws[WS_VAS + b * 64 + tid] = a;
    } else if (tid < 128) {
      const int i = tid - 64;
      float a = 0.f;
      for (int d = 0; d < OBSD; ++d) a += bf2f(s_A[i * RS + d]) * s_g[d];
      ws[WS_VE + b * 64 + i] = a;
    } else if (tid < 192) {
      const int i = tid - 128;
      float a = 0.f;
      #pragma unroll
      for (int t = 0; t < ACTD; ++t) a += s_dpa[i][t] * s_u[OBSD + t];
      ws[WS_DV + b * 64 + i] = a;
    }
  }
}

// -------- kernel 2: scores + sigmoid + sv + value + fused plane broadcast --------
// grid 512: bid = b*4 + ig; 16 i-rows per block; 3 blocks/CU (46 KB LDS).
__global__ __launch_bounds__(256, 3) void critic_sw(
    const float* __restrict__ ws, float* __restrict__ out)
{
  __shared__ __align__(16) float s_qT[DKD][64];   // [c][j]: conflict-free j-lanes
  __shared__ __align__(16) float s_k[16][132];
  __shared__ __align__(16) float s_w[16][68];
  __shared__ float s_vas[64], s_dv[64], s_ve[16], s_sv[16];

  const int t = threadIdx.x;
  const int b = blockIdx.x >> 2;
  const int i0 = (blockIdx.x & 3) * 16;

  {
    const float4* qt4 = (const float4*)(ws + WS_QT + (size_t)b * 8192);
    for (int idx = t; idx < 2048; idx += 256) {
      int c = idx >> 4, i4 = (idx & 15) * 4;
      *(float4*)&s_qT[c][i4] = qt4[idx];
    }
    const float4* k4 = (const float4*)(ws + (size_t)b * 8192 + (size_t)i0 * 128);
    for (int idx = t; idx < 512; idx += 256) {
      int r = idx >> 5, c4 = (idx & 31) * 4;
      *(float4*)&s_k[r][c4] = k4[idx];
    }
    if (t < 64)            s_vas[t] = ws[WS_VAS + b * 64 + t];
    else if (t < 128)      s_dv[t - 64] = ws[WS_DV + b * 64 + (t - 64)];
    else if (t < 144)      s_ve[t - 128] = ws[WS_VE + b * 64 + i0 + (t - 128)];
  }
  __syncthreads();

  {
    const int wv = t >> 6, j = t & 63;
    float sc0 = 0.f, sc1 = 0.f, sc2 = 0.f, sc3 = 0.f;
    #pragma unroll 4
    for (int d0 = 0; d0 < DKD; d0 += 4) {
      float q0 = s_qT[d0 + 0][j], q1 = s_qT[d0 + 1][j];
      float q2 = s_qT[d0 + 2][j], q3 = s_qT[d0 + 3][j];
      float4 k0 = *(const float4*)&s_k[wv * 4 + 0][d0];
      float4 k1 = *(const float4*)&s_k[wv * 4 + 1][d0];
      float4 k2 = *(const float4*)&s_k[wv * 4 + 2][d0];
      float4 k3 = *(const float4*)&s_k[wv * 4 + 3][d0];
      sc0 += k0.x * q0 + k0.y * q1 + k0.z * q2 + k0.w * q3;
      sc1 += k1.x * q0 + k1.y * q1 + k1.z * q2 + k1.w * q3;
      sc2 += k2.x * q0 + k2.y * q1 + k2.z * q2 + k2.w * q3;
      sc3 += k3.x * q0 + k3.y * q1 + k3.z * q2 + k3.w * q3;
    }
    const float kk = 0.08838834764831845f;  // 1/sqrt(128)
    s_w[wv * 4 + 0][j] = 1.0f / (1.0f + __expf(-sc0 * kk));
    s_w[wv * 4 + 1][j] = 1.0f / (1.0f + __expf(-sc1 * kk));
    s_w[wv * 4 + 2][j] = 1.0f / (1.0f + __expf(-sc2 * kk));
    s_w[wv * 4 + 3][j] = 1.0f / (1.0f + __expf(-sc3 * kk));
  }
  __syncthreads();

  if (t < 16) {
    float a = 0.f;
    for (int j = 0; j < 64; ++j) a += s_w[t][j] * s_vas[j];
    s_sv[t] = a;
  }
  __syncthreads();

  {
    const int r = t >> 4, m4 = (t & 15) * 4;
    float4 v;
    v.x = s_ve[r] + (s_sv[r] + s_w[r][m4 + 0] * s_dv[m4 + 0]) * (1.0f / 64.0f);
    v.y = s_ve[r] + (s_sv[r] + s_w[r][m4 + 1] * s_dv[m4 + 1]) * (1.0f / 64.0f);
    v.z = s_ve[r] + (s_sv[r] + s_w[r][m4 + 2] * s_dv[m4 + 2]) * (1.0f / 64.0f);
    v.w = s_ve[r] + (s_sv[r] + s_w[r][m4 + 3] * s_dv[m4 + 3]) * (1.0f / 64.0f);
    *(float4*)(out + ((size_t)(b * 64 + i0 + r) * 64 + m4)) = v;
  }

  // fused broadcast: 16 planes x 16 KB, REGULAR coalesced float4 stores
  float* w5 = out + (size_t)BB * NN * NN;
  #pragma unroll 4
  for (int r = 0; r < 16; ++r) {
    const float4 wv4 = *(const float4*)&s_w[r][(t & 15) * 4];
    float4* p4 = (float4*)(w5 + ((size_t)(b * 64 + i0 + r) << 12));
    p4[t]       = wv4;
    p4[t + 256] = wv4;
    p4[t + 512] = wv4;
    p4[t + 768] = wv4;
  }
}

extern "C" void kernel_launch(void* const* d_in, const int* in_sizes, int n_in,
                              void* d_out, int out_size, void* d_ws, size_t ws_size,
                              hipStream_t stream) {
  (void)in_sizes; (void)n_in; (void)out_size; (void)ws_size;
  const float* obs  = (const float*)d_in[0];
  const float* pol  = (const float*)d_in[1];
  const float* act  = (const float*)d_in[2];
  const float* Wk   = (const float*)d_in[3];
  const float* Wq   = (const float*)d_in[4];
  const float* Wv   = (const float*)d_in[5];
  const float* Wenc = (const float*)d_in[6];
  const float* Wfin = (const float*)d_in[7];
  float* out = (float*)d_out;
  float* ws  = (float*)d_ws;
  hipLaunchKernelGGL(critic_kq, dim3(BB * 2), dim3(512), 0, stream,
                     obs, pol, act, Wk, Wq, Wv, Wenc, Wfin, ws);
  hipLaunchKernelGGL(critic_sw, dim3(BB * 4), dim3(256), 0, stream, ws, out);
}